// Round 11
// baseline (157.372 us; speedup 1.0000x reference)
//
#include <hip/hip_runtime.h>
#include <hip/hip_bf16.h>

// ODEFunc: out[i] = x_N(x_i) + sum_j A[i,j] * ( edgeMLP(x_i, x_j) + wA0*x_i + wA1*x_j )
//
// R11: compiler-native v2f16 build (no inline asm — v2f16 is a legal native
// type on gfx9+, so plain C half2 arithmetic emits v_pk_fma_f16/v_pk_max_f16
// with clean SSA; R10's "=v" asm outputs forced tuple-gather movs and AGPR
// shuttling: occupancy 37% => ~170 unified regs, issue ~34 us vs ~15 static).
// Single live D (16 AGPR max) + prefetch-2 rotation to cut register footprint
// -> target ~90 unified regs, 5 waves/SIMD; cross-wave interleave hides the
// build->MFMA->epilogue chain instead of intra-wave pairing.
//
// MFMA layout (32x32x16, validated R2-R10):
//   A[m][k]: m = lane&31, k = (lane>>5)*8 + e
//   B[k][n]: n = lane&31, k = (lane>>5)*8 + e
//   D[m][n]: n = lane&31, m = (reg&3) + 8*(reg>>2) + 4*(lane>>5)
// Only m<16 carries WA1; D regs 8..15 ignored. bA1 folded into C-operand.
// In-lane epilogue: A_ij distributes into the WA2 dot; skip term in half 0 only.

#define NN 4096

typedef __fp16 half8  __attribute__((ext_vector_type(8)));
typedef __fp16 half2v __attribute__((ext_vector_type(2)));
typedef __attribute__((ext_vector_type(16))) float f32x16;

__device__ __forceinline__ half2v cvt2(float lo, float hi) {
    return __builtin_amdgcn_cvt_pkrtz(lo, hi);
}

__global__ __launch_bounds__(256, 4) void odef_kernel(
    const float* __restrict__ x,  const float* __restrict__ A,
    const float* __restrict__ WA0, const float* __restrict__ bA0,
    const float* __restrict__ WA1, const float* __restrict__ bA1,
    const float* __restrict__ WA2, const float* __restrict__ bA2,
    const float* __restrict__ Wm0, const float* __restrict__ bm0,
    const float* __restrict__ Wm1, const float* __restrict__ bm1,
    const float* __restrict__ wA,  const float* __restrict__ wf,
    float* __restrict__ out)
{
    __shared__ float partial[4];

    const int tid  = threadIdx.x;
    const int wave = tid >> 6;
    const int lane = tid & 63;
    const int n    = lane & 31;      // MFMA col (B n / D n / A m)
    const int half = lane >> 5;      // k-half (A/B), row-half (D)
    const int row  = blockIdx.x * 2 + (wave >> 1);   // 2 rows per block
    const int jbase = (wave & 1) * (NN / 2);         // 2 waves split the j range

    const float xi = x[row];

    // ---- A-fragment: WA1[m][k] in f16; m = n (<16), k = half*8 + e; rows >=16 zero
    union { half2v h2[4]; half8 h8; } au;
    #pragma unroll
    for (int p = 0; p < 4; ++p) {
        float lo = 0.f, hi = 0.f;
        if (n < 16) {
            int k = half * 8 + p * 2;
            lo = WA1[n * 16 + k];
            hi = WA1[n * 16 + k + 1];
        }
        au.h2[p] = cvt2(lo, hi);
    }

    // ---- h0 constants, packed f16: u_k(i) = WA0[k,0]*xi + bA0[k]; w1_k = WA0[k,1]
    half2v u2h[4], w2h[4];
    #pragma unroll
    for (int p = 0; p < 4; ++p) {
        int k0 = half * 8 + p * 2;
        u2h[p] = cvt2(fmaf(WA0[2 * k0],     xi, bA0[k0]),
                      fmaf(WA0[2 * k0 + 2], xi, bA0[k0 + 1]));
        w2h[p] = cvt2(WA0[2 * k0 + 1], WA0[2 * k0 + 3]);
    }

    // ---- layer-2 weights + bias-as-C for D regs 0..7 (rows (r&3)+8*(r>>2)+4*half)
    float wa2s[8];
    f32x16 cbias;
    #pragma unroll
    for (int r = 0; r < 16; ++r) cbias[r] = 0.f;
    #pragma unroll
    for (int r = 0; r < 8; ++r) {
        int m = (r & 3) + 8 * (r >> 2) + 4 * half;
        wa2s[r]  = WA2[m];
        cbias[r] = bA1[m];
    }

    // skip term: only half 0 adds it (each j is held by both halves)
    const float wA1h = half ? 0.f : wA[1];
    const float c0h  = half ? 0.f : (bA2[0] + wA[0] * xi);
    const half2v z2 = { (__fp16)0.f, (__fp16)0.f };

    const float* xp = x + jbase;
    const float* ap = A + (size_t)row * NN + jbase;

    float acc = 0.f;

    // ---- prefetch-depth-2 rotation: 64 groups of 32 j
    float xcur = xp[n],      acur = ap[n];
    float xnxt = xp[32 + n], anxt = ap[32 + n];

    #pragma unroll 4
    for (int g = 0; g < 64; ++g) {
        int gp = (g + 2 < 64) ? g + 2 : 63;      // uniform; last iters redundant
        float xpre = xp[gp * 32 + n];
        float apre = ap[gp * 32 + n];

        // build B-fragment (native v2f16 ops -> v_pk_fma_f16 / v_pk_max_f16)
        half2v xgh = cvt2(xcur, xcur);
        union { half2v h2[4]; half8 h8; } b;
        #pragma unroll
        for (int p = 0; p < 4; ++p) {
            half2v h = w2h[p] * xgh + u2h[p];
            b.h2[p] = __builtin_elementwise_max(h, z2);
        }
        f32x16 d = __builtin_amdgcn_mfma_f32_32x32x16_f16(au.h8, b.h8, cbias, 0, 0, 0);

        // scalar epilogue: pp = skip + sum_r wa2_r * relu(d_r)
        float pp = fmaf(wA1h, xcur, c0h);
        #pragma unroll
        for (int r = 0; r < 8; ++r)              // D regs 0..7 (rows < 16)
            pp = fmaf(wa2s[r], fmaxf(d[r], 0.f), pp);
        acc = fmaf(acur, pp, acc);

        xcur = xnxt; acur = anxt;
        xnxt = xpre; anxt = apre;
    }

    // ---- reduce wave, then combine the two j-half waves per row
    #pragma unroll
    for (int off = 32; off > 0; off >>= 1)
        acc += __shfl_xor(acc, off);
    if (lane == 0) partial[wave] = acc;
    __syncthreads();

    if (lane == 0 && (wave & 1) == 0) {
        // node MLP (fp32 exact): x_N = relu(x*Wm0+bm0)@Wm1 + bm1 + wf*x
        float xn = fmaf(wf[0], xi, bm1[0]);
        #pragma unroll
        for (int h = 0; h < 16; ++h)
            xn = fmaf(Wm1[h], fmaxf(fmaf(Wm0[h], xi, bm0[h]), 0.f), xn);
        out[row] = xn + partial[wave] + partial[wave + 1];
    }
}

extern "C" void kernel_launch(void* const* d_in, const int* in_sizes, int n_in,
                              void* d_out, int out_size, void* d_ws, size_t ws_size,
                              hipStream_t stream) {
    const float* x   = (const float*)d_in[1];
    const float* A   = (const float*)d_in[2];
    const float* WA0 = (const float*)d_in[3];
    const float* bA0 = (const float*)d_in[4];
    const float* WA1 = (const float*)d_in[5];
    const float* bA1 = (const float*)d_in[6];
    const float* WA2 = (const float*)d_in[7];
    const float* bA2 = (const float*)d_in[8];
    const float* Wm0 = (const float*)d_in[9];
    const float* bm0 = (const float*)d_in[10];
    const float* Wm1 = (const float*)d_in[11];
    const float* bm1 = (const float*)d_in[12];
    const float* wA  = (const float*)d_in[13];
    const float* wf  = (const float*)d_in[14];
    float* out = (float*)d_out;

    odef_kernel<<<NN / 2, 256, 0, stream>>>(x, A, WA0, bA0, WA1, bA1, WA2, bA2,
                                            Wm0, bm0, Wm1, bm1, wA, wf, out);
}

// Round 12
// 144.537 us; speedup vs baseline: 1.0888x; 1.0888x over previous
//
#include <hip/hip_runtime.h>
#include <hip/hip_bf16.h>

// ODEFunc: out[i] = x_N(x_i) + sum_j A[i,j] * ( edgeMLP(x_i, x_j) + wA0*x_i + wA1*x_j )
//
// R12 = R10's pairwise 2-deep MFMA pipeline (proven: removing it cost 17 us
// in R11) + R11's native v2f16 build (issue-neutral vs asm, cleaner SSA)
// + float4-vectorized A/x streaming: within a 128-j macro-group, lane n's
// four groups use j = j0 + 4n + q (bijection, row-sum permutation-invariant),
// so lane n loads ONE float4 of x and A per 4 MFMA groups (loads/group 2->0.5,
// address VALU /4, 2x dwordx4 wave transactions per 128 j).
//
// MFMA layout (32x32x16, validated R2-R11):
//   A[m][k]: m = lane&31, k = (lane>>5)*8 + e
//   B[k][n]: n = lane&31, k = (lane>>5)*8 + e
//   D[m][n]: n = lane&31, m = (reg&3) + 8*(reg>>2) + 4*(lane>>5)
// Only m<16 carries WA1; D regs 8..15 ignored. bA1 folded into C-operand.
// In-lane epilogue: A_ij distributes into the WA2 dot; skip term in half 0 only.

#define NN 4096

typedef __fp16 half8  __attribute__((ext_vector_type(8)));
typedef __fp16 half2v __attribute__((ext_vector_type(2)));
typedef __attribute__((ext_vector_type(4)))  float f32x4;
typedef __attribute__((ext_vector_type(16))) float f32x16;

__device__ __forceinline__ half2v cvt2(float lo, float hi) {
    return __builtin_amdgcn_cvt_pkrtz(lo, hi);
}

__global__ __launch_bounds__(256, 4) void odef_kernel(
    const float* __restrict__ x,  const float* __restrict__ A,
    const float* __restrict__ WA0, const float* __restrict__ bA0,
    const float* __restrict__ WA1, const float* __restrict__ bA1,
    const float* __restrict__ WA2, const float* __restrict__ bA2,
    const float* __restrict__ Wm0, const float* __restrict__ bm0,
    const float* __restrict__ Wm1, const float* __restrict__ bm1,
    const float* __restrict__ wA,  const float* __restrict__ wf,
    float* __restrict__ out)
{
    __shared__ float partial[4];

    const int tid  = threadIdx.x;
    const int wave = tid >> 6;
    const int lane = tid & 63;
    const int n    = lane & 31;      // MFMA col (B n / D n / A m)
    const int half = lane >> 5;      // k-half (A/B), row-half (D)
    const int row  = blockIdx.x * 2 + (wave >> 1);   // 2 rows per block
    const int jbase = (wave & 1) * (NN / 2);         // 2 waves split the j range

    const float xi = x[row];

    // ---- A-fragment: WA1[m][k] in f16; m = n (<16), k = half*8 + e; rows >=16 zero
    union { half2v h2[4]; half8 h8; } au;
    #pragma unroll
    for (int p = 0; p < 4; ++p) {
        float lo = 0.f, hi = 0.f;
        if (n < 16) {
            int k = half * 8 + p * 2;
            lo = WA1[n * 16 + k];
            hi = WA1[n * 16 + k + 1];
        }
        au.h2[p] = cvt2(lo, hi);
    }

    // ---- h0 constants, packed f16: u_k(i) = WA0[k,0]*xi + bA0[k]; w1_k = WA0[k,1]
    half2v u2h[4], w2h[4];
    #pragma unroll
    for (int p = 0; p < 4; ++p) {
        int k0 = half * 8 + p * 2;
        u2h[p] = cvt2(fmaf(WA0[2 * k0],     xi, bA0[k0]),
                      fmaf(WA0[2 * k0 + 2], xi, bA0[k0 + 1]));
        w2h[p] = cvt2(WA0[2 * k0 + 1], WA0[2 * k0 + 3]);
    }

    // ---- layer-2 weights + bias-as-C for D regs 0..7 (rows (r&3)+8*(r>>2)+4*half)
    float wa2s[8];
    f32x16 cbias;
    #pragma unroll
    for (int r = 0; r < 16; ++r) cbias[r] = 0.f;
    #pragma unroll
    for (int r = 0; r < 8; ++r) {
        int m = (r & 3) + 8 * (r >> 2) + 4 * half;
        wa2s[r]  = WA2[m];
        cbias[r] = bA1[m];
    }

    // skip term: only half 0 adds it (each j is held by both halves)
    const float wA1h = half ? 0.f : wA[1];
    const float c0h  = half ? 0.f : (bA2[0] + wA[0] * xi);
    const half2v z2 = { (__fp16)0.f, (__fp16)0.f };

    // lane n streams j = jbase + it*128 + 4n + q as one float4 per macro-iter
    const f32x4* xp4 = (const f32x4*)(x + jbase) + n;
    const f32x4* ap4 = (const f32x4*)(A + (size_t)row * NN + jbase) + n;

    float acc = 0.f;

    // ---- 16 macro-iters x 128 j (4 MFMA groups), prefetch-1-macro pipeline
    f32x4 xc = xp4[0];
    f32x4 ac = ap4[0];

    for (int it = 0; it < 16; ++it) {
        const f32x4* xnp = (it + 1 < 16) ? xp4 + 32 : xp4;   // 32 float4 = 128 floats
        const f32x4* anp = (it + 1 < 16) ? ap4 + 32 : ap4;
        f32x4 xN = xnp[0];
        f32x4 aN = anp[0];

        #pragma unroll
        for (int q = 0; q < 4; q += 2) {
            // build + MFMA for group q (native v2f16 -> v_pk_fma/max_f16)
            half2v xgh0 = cvt2(xc[q], xc[q]);
            union { half2v h2[4]; half8 h8; } b0;
            #pragma unroll
            for (int p = 0; p < 4; ++p)
                b0.h2[p] = __builtin_elementwise_max(w2h[p] * xgh0 + u2h[p], z2);
            f32x16 d0 = __builtin_amdgcn_mfma_f32_32x32x16_f16(au.h8, b0.h8, cbias, 0, 0, 0);

            // build + MFMA for group q+1 (covers MFMA0 + D-read latency)
            half2v xgh1 = cvt2(xc[q + 1], xc[q + 1]);
            union { half2v h2[4]; half8 h8; } b1;
            #pragma unroll
            for (int p = 0; p < 4; ++p)
                b1.h2[p] = __builtin_elementwise_max(w2h[p] * xgh1 + u2h[p], z2);
            f32x16 d1 = __builtin_amdgcn_mfma_f32_32x32x16_f16(au.h8, b1.h8, cbias, 0, 0, 0);

            // epilogue q
            {
                float pp = fmaf(wA1h, xc[q], c0h);
                #pragma unroll
                for (int r = 0; r < 8; ++r)          // D regs 0..7 (rows < 16)
                    pp = fmaf(wa2s[r], fmaxf(d0[r], 0.f), pp);
                acc = fmaf(ac[q], pp, acc);
            }
            // epilogue q+1
            {
                float pp = fmaf(wA1h, xc[q + 1], c0h);
                #pragma unroll
                for (int r = 0; r < 8; ++r)
                    pp = fmaf(wa2s[r], fmaxf(d1[r], 0.f), pp);
                acc = fmaf(ac[q + 1], pp, acc);
            }
        }
        xc = xN; ac = aN;
        xp4 = xnp; ap4 = anp;
    }

    // ---- reduce wave, then combine the two j-half waves per row
    #pragma unroll
    for (int off = 32; off > 0; off >>= 1)
        acc += __shfl_xor(acc, off);
    if (lane == 0) partial[wave] = acc;
    __syncthreads();

    if (lane == 0 && (wave & 1) == 0) {
        // node MLP (fp32 exact): x_N = relu(x*Wm0+bm0)@Wm1 + bm1 + wf*x
        float xn = fmaf(wf[0], xi, bm1[0]);
        #pragma unroll
        for (int h = 0; h < 16; ++h)
            xn = fmaf(Wm1[h], fmaxf(fmaf(Wm0[h], xi, bm0[h]), 0.f), xn);
        out[row] = xn + partial[wave] + partial[wave + 1];
    }
}

extern "C" void kernel_launch(void* const* d_in, const int* in_sizes, int n_in,
                              void* d_out, int out_size, void* d_ws, size_t ws_size,
                              hipStream_t stream) {
    const float* x   = (const float*)d_in[1];
    const float* A   = (const float*)d_in[2];
    const float* WA0 = (const float*)d_in[3];
    const float* bA0 = (const float*)d_in[4];
    const float* WA1 = (const float*)d_in[5];
    const float* bA1 = (const float*)d_in[6];
    const float* WA2 = (const float*)d_in[7];
    const float* bA2 = (const float*)d_in[8];
    const float* Wm0 = (const float*)d_in[9];
    const float* bm0 = (const float*)d_in[10];
    const float* Wm1 = (const float*)d_in[11];
    const float* bm1 = (const float*)d_in[12];
    const float* wA  = (const float*)d_in[13];
    const float* wf  = (const float*)d_in[14];
    float* out = (float*)d_out;

    odef_kernel<<<NN / 2, 256, 0, stream>>>(x, A, WA0, bA0, WA1, bA1, WA2, bA2,
                                            Wm0, bm0, Wm1, bm1, wA, wf, out);
}